// Round 1
// baseline (775.003 us; speedup 1.0000x reference)
//
#include <hip/hip_runtime.h>
#include <hip/hip_bf16.h>
#include <cstdint>

typedef unsigned short u16;
typedef __bf16 bf16x8 __attribute__((ext_vector_type(8)));
typedef float f32x4 __attribute__((ext_vector_type(4)));

__device__ __forceinline__ u16 f2bf(float f) {
  unsigned int u = __float_as_uint(f);
  u += 0x7FFFu + ((u >> 16) & 1u);
  return (u16)(u >> 16);
}
__device__ __forceinline__ unsigned int pack2(float a, float b) {
  return (unsigned int)f2bf(a) | ((unsigned int)f2bf(b) << 16);
}

// ---------------- cast fp32 -> bf16 (vectorized) ----------------
__global__ __launch_bounds__(256) void cast_bf16_k(const float* __restrict__ in,
                                                   u16* __restrict__ out) {
  const int i = (blockIdx.x * 256 + threadIdx.x) * 4;
  const float4 v = *(const float4*)(in + i);
  uint2 p;
  p.x = pack2(v.x, v.y);
  p.y = pack2(v.z, v.w);
  *(uint2*)(out + i) = p;
}

// ---------------- transpose + cast: in[R][C] fp32 -> out[C][R] bf16 ----------------
__global__ __launch_bounds__(256) void transpose_cast_k(const float* __restrict__ in,
                                                        u16* __restrict__ out,
                                                        int R, int C) {
  __shared__ float tile[32][33];
  const int bx = blockIdx.x * 32, by = blockIdx.y * 32;
  const int tx = threadIdx.x & 31, ty = threadIdx.x >> 5;  // ty 0..7
#pragma unroll
  for (int i = 0; i < 32; i += 8)
    tile[ty + i][tx] = in[(size_t)(by + ty + i) * C + (bx + tx)];
  __syncthreads();
#pragma unroll
  for (int i = 0; i < 32; i += 8)
    out[(size_t)(bx + ty + i) * R + (by + tx)] = f2bf(tile[tx][ty + i]);
}

// ---------------- GEMM: C[M,N] = A[M,K](bf16) @ Bt[N,K](bf16)^T + bias, epilogues ----------------
// EPI 0: QKV scatter -> Q[bh][t][d], K[bh][t][d], Vt[bh][d][t] (bf16)
// EPI 1: out_f[row*N+col] = acc + bias + resid[row*N+col]   (fp32)
// EPI 2: out_b[row*N+col] = bf16(gelu_exact(acc + bias))
#define BM 128
#define BN 128
#define BK 32

template <int EPI>
__global__ __launch_bounds__(256) void gemm_bt(
    const u16* __restrict__ A, const u16* __restrict__ Bt,
    const float* __restrict__ bias, const float* __restrict__ resid,
    float* __restrict__ out_f, u16* __restrict__ out_b,
    u16* __restrict__ q_out, u16* __restrict__ k_out, u16* __restrict__ vt_out,
    int M, int N, int K) {
  __shared__ u16 As[BM * BK];
  __shared__ u16 Bs[BN * BK];
  const int tid = threadIdx.x;
  const int wave = tid >> 6, lane = tid & 63;
  const int lhi = lane >> 4, llo = lane & 15;
  const int m0 = blockIdx.y * BM, n0 = blockIdx.x * BN;
  const int wr = (wave >> 1) * 64, wc = (wave & 1) * 64;

  f32x4 acc[4][4] = {};

  const int c0 = wave * 64 + lane;  // staging chunk id, i=0
  for (int k0 = 0; k0 < K; k0 += BK) {
    __syncthreads();
#pragma unroll
    for (int i = 0; i < 2; ++i) {
      const int c = c0 + i * 256;          // 0..511 : 16B chunk of the 128x32 tile
      const int r = c >> 2, sub = c & 3;   // row, 8-elem group
      const u16* ga = A + (size_t)(m0 + r) * K + (k0 + sub * 8);
      const u16* gb = Bt + (size_t)(n0 + r) * K + (k0 + sub * 8);
      __builtin_amdgcn_global_load_lds(
          (const __attribute__((address_space(1))) unsigned int*)ga,
          (__attribute__((address_space(3))) unsigned int*)(As + (wave * 64 + i * 256) * 8),
          16, 0, 0);
      __builtin_amdgcn_global_load_lds(
          (const __attribute__((address_space(1))) unsigned int*)gb,
          (__attribute__((address_space(3))) unsigned int*)(Bs + (wave * 64 + i * 256) * 8),
          16, 0, 0);
    }
    __syncthreads();
    bf16x8 af[4], bfr[4];
#pragma unroll
    for (int mf = 0; mf < 4; ++mf)
      af[mf] = *(const bf16x8*)(As + (wr + mf * 16 + llo) * BK + lhi * 8);
#pragma unroll
    for (int nf = 0; nf < 4; ++nf)
      bfr[nf] = *(const bf16x8*)(Bs + (wc + nf * 16 + llo) * BK + lhi * 8);
#pragma unroll
    for (int mf = 0; mf < 4; ++mf)
#pragma unroll
      for (int nf = 0; nf < 4; ++nf)
        acc[mf][nf] =
            __builtin_amdgcn_mfma_f32_16x16x32_bf16(af[mf], bfr[nf], acc[mf][nf], 0, 0, 0);
  }

#pragma unroll
  for (int mf = 0; mf < 4; ++mf) {
#pragma unroll
    for (int nf = 0; nf < 4; ++nf) {
      const int col = n0 + wc + nf * 16 + llo;
      const int rowb = m0 + wr + mf * 16 + lhi * 4;
      const float bv = bias[col];
#pragma unroll
      for (int r = 0; r < 4; ++r) {
        const int row = rowb + r;
        const float v = acc[mf][nf][r] + bv;
        if (EPI == 0) {
          const int which = col >> 10, rem = col & 1023;
          const int h = rem >> 6, d = rem & 63;
          const int b = row >> 10, t = row & 1023;
          const size_t bh = (size_t)(b * 16 + h);
          const u16 u = f2bf(v);
          if (which == 0)
            q_out[(bh * 1024 + t) * 64 + d] = u;
          else if (which == 1)
            k_out[(bh * 1024 + t) * 64 + d] = u;
          else
            vt_out[(bh * 64 + d) * 1024 + t] = u;
        } else if (EPI == 1) {
          out_f[(size_t)row * N + col] = v + resid[(size_t)row * N + col];
        } else {
          const float gl = 0.5f * v * (1.0f + erff(v * 0.70710678118f));
          out_b[(size_t)row * N + col] = f2bf(gl);
        }
      }
    }
  }
}

// ---------------- fused attention: one block = (bh, 16 q-rows) ----------------
// S[16][1024] fp32 in LDS (stride 1032 to dodge bank conflicts); softmax row-parallel;
// P (normalized, bf16, XOR-swizzled) overwrites the same LDS; PV via MFMA with Vt.
__global__ __launch_bounds__(256) void attn_k(const u16* __restrict__ Qb,
                                              const u16* __restrict__ Kb,
                                              const u16* __restrict__ Vt,
                                              u16* __restrict__ ctx) {
  __shared__ float S[16 * 1032];
  const int tid = threadIdx.x;
  const int wave = tid >> 6, lane = tid & 63;
  const int lhi = lane >> 4, llo = lane & 15;
  const int bh = blockIdx.y;
  const int q0 = blockIdx.x * 16;
  const size_t hq = (size_t)bh * 1024 * 64;

  // Q fragments (A operand): row = llo, k = kc*32 + lhi*8 + j
  const u16* qptr = Qb + hq + (size_t)(q0 + llo) * 64 + lhi * 8;
  const bf16x8 qf0 = *(const bf16x8*)(qptr);
  const bf16x8 qf1 = *(const bf16x8*)(qptr + 32);

  // Phase 1: S = (Q @ K^T) / 8 ; each wave covers 256 score-cols (16 blocks of 16)
#pragma unroll 4
  for (int cbi = 0; cbi < 16; ++cbi) {
    const int cb = wave * 16 + cbi;
    const u16* kptr = Kb + hq + (size_t)(cb * 16 + llo) * 64 + lhi * 8;
    const bf16x8 kf0 = *(const bf16x8*)(kptr);
    const bf16x8 kf1 = *(const bf16x8*)(kptr + 32);
    f32x4 acc = {};
    acc = __builtin_amdgcn_mfma_f32_16x16x32_bf16(qf0, kf0, acc, 0, 0, 0);
    acc = __builtin_amdgcn_mfma_f32_16x16x32_bf16(qf1, kf1, acc, 0, 0, 0);
#pragma unroll
    for (int r = 0; r < 4; ++r)
      S[(lhi * 4 + r) * 1032 + cb * 16 + llo] = acc[r] * 0.125f;
  }
  __syncthreads();

  // Phase 2: softmax. 16 threads per row, 64 strided cols each (bank-friendly).
  const int row = tid >> 4, i16 = tid & 15;
  const float* srow = S + row * 1032;
  float vals[64];
  float mx = -3.0e38f;
#pragma unroll
  for (int j = 0; j < 16; ++j) {
    const float4 v = *(const float4*)(srow + i16 * 4 + j * 64);
    vals[4 * j] = v.x; vals[4 * j + 1] = v.y; vals[4 * j + 2] = v.z; vals[4 * j + 3] = v.w;
    mx = fmaxf(mx, fmaxf(fmaxf(v.x, v.y), fmaxf(v.z, v.w)));
  }
#pragma unroll
  for (int m = 1; m < 16; m <<= 1) mx = fmaxf(mx, __shfl_xor(mx, m));
  float sum = 0.f;
#pragma unroll
  for (int j = 0; j < 64; ++j) {
    const float e = __expf(vals[j] - mx);
    vals[j] = e;
    sum += e;
  }
#pragma unroll
  for (int m = 1; m < 16; m <<= 1) sum += __shfl_xor(sum, m);
  const float inv = 1.0f / sum;
  __syncthreads();  // all S reads done before P overwrites the buffer
  u16* P = (u16*)S;  // P row stride = 2048 B, XOR-swizzled by ((row&7)<<4)
#pragma unroll
  for (int j = 0; j < 16; ++j) {
    uint2 pk;
    pk.x = pack2(vals[4 * j] * inv, vals[4 * j + 1] * inv);
    pk.y = pack2(vals[4 * j + 2] * inv, vals[4 * j + 3] * inv);
    int byte = row * 2048 + (i16 * 4 + j * 64) * 2;
    byte ^= (row & 7) << 4;
    *(uint2*)((char*)P + byte) = pk;
  }
  __syncthreads();

  // Phase 3: ctx = P @ V. Wave w covers d-cols [w*16, w*16+16).
  const u16* vptr = Vt + (size_t)bh * 64 * 1024 + (size_t)(wave * 16 + llo) * 1024 + lhi * 8;
  f32x4 acc3 = {};
#pragma unroll 8
  for (int kc = 0; kc < 32; ++kc) {
    int byte = llo * 2048 + (kc * 32 + lhi * 8) * 2;
    byte ^= (llo & 7) << 4;
    const bf16x8 pf = *(const bf16x8*)((const char*)P + byte);
    const bf16x8 vf = *(const bf16x8*)(vptr + kc * 32);
    acc3 = __builtin_amdgcn_mfma_f32_16x16x32_bf16(pf, vf, acc3, 0, 0, 0);
  }
  const int b = bh >> 4, h = bh & 15;
#pragma unroll
  for (int r = 0; r < 4; ++r) {
    const int t = q0 + lhi * 4 + r;
    ctx[((size_t)(b * 1024 + t)) * 1024 + h * 64 + wave * 16 + llo] = f2bf(acc3[r]);
  }
}

// ---------------- LayerNorm over D=1024; writes bf16 and/or fp32 ----------------
__global__ __launch_bounds__(256) void layernorm_k(const float* __restrict__ y,
                                                   const float* __restrict__ g,
                                                   const float* __restrict__ be,
                                                   u16* __restrict__ out_b,
                                                   float* __restrict__ out_f) {
  const int row = blockIdx.x;
  const int t = threadIdx.x;
  const float* yr = y + (size_t)row * 1024;
  const float4 v = *(const float4*)(yr + t * 4);
  float s = v.x + v.y + v.z + v.w;
  float s2 = v.x * v.x + v.y * v.y + v.z * v.z + v.w * v.w;
#pragma unroll
  for (int m = 1; m < 64; m <<= 1) {
    s += __shfl_xor(s, m);
    s2 += __shfl_xor(s2, m);
  }
  __shared__ float red[8];
  const int wv = t >> 6, lane = t & 63;
  if (lane == 0) {
    red[wv * 2] = s;
    red[wv * 2 + 1] = s2;
  }
  __syncthreads();
  s = red[0] + red[2] + red[4] + red[6];
  s2 = red[1] + red[3] + red[5] + red[7];
  const float mu = s * (1.0f / 1024.0f);
  const float var = s2 * (1.0f / 1024.0f) - mu * mu;
  const float inv = rsqrtf(var + 1e-5f);
  const int c = t * 4;
  const float4 gg = *(const float4*)(g + c);
  const float4 bb = *(const float4*)(be + c);
  const float o0 = (v.x - mu) * inv * gg.x + bb.x;
  const float o1 = (v.y - mu) * inv * gg.y + bb.y;
  const float o2 = (v.z - mu) * inv * gg.z + bb.z;
  const float o3 = (v.w - mu) * inv * gg.w + bb.w;
  if (out_f) {
    float4 o = {o0, o1, o2, o3};
    *(float4*)(out_f + (size_t)row * 1024 + c) = o;
  }
  if (out_b) {
    uint2 p;
    p.x = pack2(o0, o1);
    p.y = pack2(o2, o3);
    *(uint2*)(out_b + (size_t)row * 1024 + c) = p;
  }
}

// ---------------- launch ----------------
extern "C" void kernel_launch(void* const* d_in, const int* in_sizes, int n_in,
                              void* d_out, int out_size, void* d_ws, size_t ws_size,
                              hipStream_t stream) {
  const float* X = (const float*)d_in[0];
  const float* W_qkv = (const float*)d_in[1];
  const float* b_qkv = (const float*)d_in[2];
  const float* W_out = (const float*)d_in[3];
  const float* b_out = (const float*)d_in[4];
  const float* ln1_g = (const float*)d_in[5];
  const float* ln1_b = (const float*)d_in[6];
  const float* ln2_g = (const float*)d_in[7];
  const float* ln2_b = (const float*)d_in[8];
  const float* W_ff1 = (const float*)d_in[9];
  const float* b_ff1 = (const float*)d_in[10];
  const float* W_ff2 = (const float*)d_in[11];
  const float* b_ff2 = (const float*)d_in[12];

  char* ws = (char*)d_ws;
  size_t off = 0;
  auto alloc = [&](size_t bytes) {
    char* p = ws + off;
    off += (bytes + 255) & ~(size_t)255;
    return p;
  };
  u16* Xb = (u16*)alloc(8192ull * 1024 * 2);       // X bf16
  u16* Wqkvt = (u16*)alloc(3072ull * 1024 * 2);    // W_qkv^T bf16
  u16* Woutt = (u16*)alloc(1024ull * 1024 * 2);    // W_out^T bf16
  u16* Wff1t = (u16*)alloc(4096ull * 1024 * 2);    // W_ff1^T bf16
  u16* Wff2t = (u16*)alloc(1024ull * 4096 * 2);    // W_ff2^T bf16
  u16* Qb = (u16*)alloc(128ull * 1024 * 64 * 2);   // Q [bh][t][d]
  u16* Kb = (u16*)alloc(128ull * 1024 * 64 * 2);   // K [bh][t][d]
  u16* Vtb = (u16*)alloc(128ull * 1024 * 64 * 2);  // V^T [bh][d][t]
  u16* ctx = (u16*)alloc(8192ull * 1024 * 2);      // attention context bf16
  float* y1 = (float*)alloc(8192ull * 1024 * 4);   // pre-LN1 residual sum; reused as y2
  u16* X1b = (u16*)alloc(8192ull * 1024 * 2);      // LN1 out bf16
  float* X1f = (float*)alloc(8192ull * 1024 * 4);  // LN1 out fp32
  u16* hbuf = Qb;  // FF1 output (64 MB) aliases Qb..ctx (dead after out-proj)

  cast_bf16_k<<<8192, 256, 0, stream>>>(X, Xb);
  transpose_cast_k<<<dim3(96, 32), 256, 0, stream>>>(W_qkv, Wqkvt, 1024, 3072);
  transpose_cast_k<<<dim3(32, 32), 256, 0, stream>>>(W_out, Woutt, 1024, 1024);
  transpose_cast_k<<<dim3(128, 32), 256, 0, stream>>>(W_ff1, Wff1t, 1024, 4096);
  transpose_cast_k<<<dim3(32, 128), 256, 0, stream>>>(W_ff2, Wff2t, 4096, 1024);

  // QKV projection + head scatter
  gemm_bt<0><<<dim3(24, 64), 256, 0, stream>>>(Xb, Wqkvt, b_qkv, nullptr, nullptr, nullptr,
                                               Qb, Kb, Vtb, 8192, 3072, 1024);
  // attention
  attn_k<<<dim3(64, 128), 256, 0, stream>>>(Qb, Kb, Vtb, ctx);
  // out projection + bias + residual(X) -> y1 fp32
  gemm_bt<1><<<dim3(8, 64), 256, 0, stream>>>(ctx, Woutt, b_out, X, y1, nullptr,
                                              nullptr, nullptr, nullptr, 8192, 1024, 1024);
  // LN1 -> X1 (bf16 + fp32)
  layernorm_k<<<8192, 256, 0, stream>>>(y1, ln1_g, ln1_b, X1b, X1f);
  // FF1 + bias + exact GELU -> h bf16
  gemm_bt<2><<<dim3(32, 64), 256, 0, stream>>>(X1b, Wff1t, b_ff1, nullptr, nullptr, hbuf,
                                               nullptr, nullptr, nullptr, 8192, 4096, 1024);
  // FF2 + bias + residual(X1) -> y2 fp32 (reuse y1 buffer)
  gemm_bt<1><<<dim3(8, 64), 256, 0, stream>>>(hbuf, Wff2t, b_ff2, X1f, y1, nullptr,
                                              nullptr, nullptr, nullptr, 8192, 1024, 4096);
  // LN2 -> output fp32
  layernorm_k<<<8192, 256, 0, stream>>>(y1, ln2_g, ln2_b, nullptr, (float*)d_out);
}

// Round 2
// 597.258 us; speedup vs baseline: 1.2976x; 1.2976x over previous
//
#include <hip/hip_runtime.h>
#include <hip/hip_bf16.h>
#include <cstdint>

typedef unsigned short u16;
typedef __bf16 bf16x8 __attribute__((ext_vector_type(8)));
typedef float f32x4 __attribute__((ext_vector_type(4)));

__device__ __forceinline__ u16 f2bf(float f) {
  unsigned int u = __float_as_uint(f);
  u += 0x7FFFu + ((u >> 16) & 1u);
  return (u16)(u >> 16);
}
__device__ __forceinline__ unsigned int pack2(float a, float b) {
  return (unsigned int)f2bf(a) | ((unsigned int)f2bf(b) << 16);
}

// ---------------- cast fp32 -> bf16 (vectorized) ----------------
__global__ __launch_bounds__(256) void cast_bf16_k(const float* __restrict__ in,
                                                   u16* __restrict__ out) {
  const int i = (blockIdx.x * 256 + threadIdx.x) * 4;
  const float4 v = *(const float4*)(in + i);
  uint2 p;
  p.x = pack2(v.x, v.y);
  p.y = pack2(v.z, v.w);
  *(uint2*)(out + i) = p;
}

// ---------------- transpose + cast: in[R][C] fp32 -> out[C][R] bf16 ----------------
__global__ __launch_bounds__(256) void transpose_cast_k(const float* __restrict__ in,
                                                        u16* __restrict__ out,
                                                        int R, int C) {
  __shared__ float tile[32][33];
  const int bx = blockIdx.x * 32, by = blockIdx.y * 32;
  const int tx = threadIdx.x & 31, ty = threadIdx.x >> 5;  // ty 0..7
#pragma unroll
  for (int i = 0; i < 32; i += 8)
    tile[ty + i][tx] = in[(size_t)(by + ty + i) * C + (bx + tx)];
  __syncthreads();
#pragma unroll
  for (int i = 0; i < 32; i += 8)
    out[(size_t)(bx + ty + i) * R + (by + tx)] = f2bf(tile[tx][ty + i]);
}

// ---------------- GEMM: C[M,N] = A[M,K](bf16) @ Bt[N,K](bf16)^T + bias, epilogues ----------------
#define BM 128
#define BN 128
#define BK 32

template <int EPI>
__global__ __launch_bounds__(256) void gemm_bt(
    const u16* __restrict__ A, const u16* __restrict__ Bt,
    const float* __restrict__ bias, const float* __restrict__ resid,
    float* __restrict__ out_f, u16* __restrict__ out_b,
    u16* __restrict__ q_out, u16* __restrict__ k_out, u16* __restrict__ vt_out,
    int M, int N, int K) {
  __shared__ u16 As[BM * BK];
  __shared__ u16 Bs[BN * BK];
  const int tid = threadIdx.x;
  const int wave = tid >> 6, lane = tid & 63;
  const int lhi = lane >> 4, llo = lane & 15;
  const int m0 = blockIdx.y * BM, n0 = blockIdx.x * BN;
  const int wr = (wave >> 1) * 64, wc = (wave & 1) * 64;

  f32x4 acc[4][4] = {};

  const int c0 = wave * 64 + lane;  // staging chunk id, i=0
  for (int k0 = 0; k0 < K; k0 += BK) {
    __syncthreads();
#pragma unroll
    for (int i = 0; i < 2; ++i) {
      const int c = c0 + i * 256;          // 0..511 : 16B chunk of the 128x32 tile
      const int r = c >> 2, sub = c & 3;   // row, 8-elem group
      const u16* ga = A + (size_t)(m0 + r) * K + (k0 + sub * 8);
      const u16* gb = Bt + (size_t)(n0 + r) * K + (k0 + sub * 8);
      __builtin_amdgcn_global_load_lds(
          (const __attribute__((address_space(1))) unsigned int*)ga,
          (__attribute__((address_space(3))) unsigned int*)(As + (wave * 64 + i * 256) * 8),
          16, 0, 0);
      __builtin_amdgcn_global_load_lds(
          (const __attribute__((address_space(1))) unsigned int*)gb,
          (__attribute__((address_space(3))) unsigned int*)(Bs + (wave * 64 + i * 256) * 8),
          16, 0, 0);
    }
    __syncthreads();
    bf16x8 af[4], bfr[4];
#pragma unroll
    for (int mf = 0; mf < 4; ++mf)
      af[mf] = *(const bf16x8*)(As + (wr + mf * 16 + llo) * BK + lhi * 8);
#pragma unroll
    for (int nf = 0; nf < 4; ++nf)
      bfr[nf] = *(const bf16x8*)(Bs + (wc + nf * 16 + llo) * BK + lhi * 8);
#pragma unroll
    for (int mf = 0; mf < 4; ++mf)
#pragma unroll
      for (int nf = 0; nf < 4; ++nf)
        acc[mf][nf] =
            __builtin_amdgcn_mfma_f32_16x16x32_bf16(af[mf], bfr[nf], acc[mf][nf], 0, 0, 0);
  }

#pragma unroll
  for (int mf = 0; mf < 4; ++mf) {
#pragma unroll
    for (int nf = 0; nf < 4; ++nf) {
      const int col = n0 + wc + nf * 16 + llo;
      const int rowb = m0 + wr + mf * 16 + lhi * 4;
      const float bv = bias[col];
#pragma unroll
      for (int r = 0; r < 4; ++r) {
        const int row = rowb + r;
        const float v = acc[mf][nf][r] + bv;
        if (EPI == 0) {
          const int which = col >> 10, rem = col & 1023;
          const int h = rem >> 6, d = rem & 63;
          const int b = row >> 10, t = row & 1023;
          const size_t bh = (size_t)(b * 16 + h);
          const u16 u = f2bf(v);
          if (which == 0)
            q_out[(bh * 1024 + t) * 64 + d] = u;
          else if (which == 1)
            k_out[(bh * 1024 + t) * 64 + d] = u;
          else
            vt_out[(bh * 64 + d) * 1024 + t] = u;
        } else if (EPI == 1) {
          out_f[(size_t)row * N + col] = v + resid[(size_t)row * N + col];
        } else {
          const float gl = 0.5f * v * (1.0f + erff(v * 0.70710678118f));
          out_b[(size_t)row * N + col] = f2bf(gl);
        }
      }
    }
  }
}

// ---------------- flash attention: block = (bh, 64 q-rows), 4 waves x 16 q ----------------
// Swapped QK^T (mfma(K,Q)) and O^T = V^T P^T keep q = lane&15 lane-local for S, m, l, O.
// K/V tiles (64 x 64 bf16 = 8KB each) staged via global_load_lds with pre-swizzled
// source; all LDS rows are 128B with XOR swizzle byte ^= ((row&7)<<4).
__global__ __launch_bounds__(256) void attn_flash_k(const u16* __restrict__ Qb,
                                                    const u16* __restrict__ Kb,
                                                    const u16* __restrict__ Vt,
                                                    u16* __restrict__ ctx) {
  __shared__ char lds[8192 + 8192 + 4 * 2048];
  char* Ks = lds;
  char* Vs = lds + 8192;
  const int tid = threadIdx.x;
  const int wave = tid >> 6, lane = tid & 63;
  const int llo = lane & 15, lhi = lane >> 4;
  char* Ps = lds + 16384 + wave * 2048;  // per-wave P scratch [16 q][128B]
  const int bh = blockIdx.y;
  const int q0 = blockIdx.x * 64 + wave * 16;
  const size_t hq = (size_t)bh * 1024 * 64;
  const int swz = (llo & 7) << 4;

  // Q fragments for q = q0 + llo  (B-operand of swapped QK^T)
  const u16* qrow = Qb + hq + (size_t)(q0 + llo) * 64;
  const bf16x8 qf0 = *(const bf16x8*)(qrow + lhi * 8);
  const bf16x8 qf1 = *(const bf16x8*)(qrow + 32 + lhi * 8);

  f32x4 O[4] = {};
  float m = -3.0e38f, l = 0.f;
  const float C = 0.18033688011112042f;  // 0.125 * log2(e)

  for (int t = 0; t < 16; ++t) {
    const int kv0 = t * 64;
    __syncthreads();  // previous tile's LDS reads complete
#pragma unroll
    for (int j = 0; j < 2; ++j) {
      const int p = (j * 256 + tid) * 16;            // dest byte (linear)
      const int r = p >> 7;                          // LDS row 0..63
      const int c = (p & 127) ^ ((r & 7) << 4);      // pre-swizzled source col (bytes)
      const u16* gk = Kb + hq + (size_t)(kv0 + r) * 64 + (c >> 1);
      __builtin_amdgcn_global_load_lds(
          (const __attribute__((address_space(1))) unsigned int*)gk,
          (__attribute__((address_space(3))) unsigned int*)(Ks + (j * 256 + wave * 64) * 16),
          16, 0, 0);
      const u16* gv = Vt + (size_t)bh * 64 * 1024 + (size_t)r * 1024 + kv0 + (c >> 1);
      __builtin_amdgcn_global_load_lds(
          (const __attribute__((address_space(1))) unsigned int*)gv,
          (__attribute__((address_space(3))) unsigned int*)(Vs + (j * 256 + wave * 64) * 16),
          16, 0, 0);
    }
    __syncthreads();  // staged data visible

    // QK^T: S[k][q] tiles; lane holds q=llo, k = kt*16 + lhi*4 + r
    f32x4 s[4];
#pragma unroll
    for (int kt = 0; kt < 4; ++kt) {
      const int row = kt * 16 + llo;
      const bf16x8 k0 = *(const bf16x8*)(Ks + row * 128 + ((lhi * 16) ^ swz));
      const bf16x8 k1 = *(const bf16x8*)(Ks + row * 128 + ((64 + lhi * 16) ^ swz));
      f32x4 a = {};
      a = __builtin_amdgcn_mfma_f32_16x16x32_bf16(k0, qf0, a, 0, 0, 0);
      a = __builtin_amdgcn_mfma_f32_16x16x32_bf16(k1, qf1, a, 0, 0, 0);
      s[kt] = a;
    }

    // online softmax (raw scores; 1/8 folded into exp2 constant)
    float tmax = -3.0e38f;
#pragma unroll
    for (int kt = 0; kt < 4; ++kt)
#pragma unroll
      for (int r = 0; r < 4; ++r) tmax = fmaxf(tmax, s[kt][r]);
    tmax = fmaxf(tmax, __shfl_xor(tmax, 16));
    tmax = fmaxf(tmax, __shfl_xor(tmax, 32));
    const float mnew = fmaxf(m, tmax);
    const float sc = exp2f((m - mnew) * C);
    float tsum = 0.f;
#pragma unroll
    for (int kt = 0; kt < 4; ++kt)
#pragma unroll
      for (int r = 0; r < 4; ++r) {
        const float pv = exp2f((s[kt][r] - mnew) * C);
        s[kt][r] = pv;
        tsum += pv;
      }
    tsum += __shfl_xor(tsum, 16);
    tsum += __shfl_xor(tsum, 32);
    l = l * sc + tsum;
    m = mnew;
#pragma unroll
    for (int dt = 0; dt < 4; ++dt) O[dt] *= sc;

    // P (bf16) -> wave-local LDS, re-fragment k-quads into k-octets
#pragma unroll
    for (int kt = 0; kt < 4; ++kt) {
      uint2 pk;
      pk.x = pack2(s[kt][0], s[kt][1]);
      pk.y = pack2(s[kt][2], s[kt][3]);
      *(uint2*)(Ps + llo * 128 + ((kt * 32 + lhi * 8) ^ swz)) = pk;
    }
    bf16x8 pb[2];
#pragma unroll
    for (int kc = 0; kc < 2; ++kc)
      pb[kc] = *(const bf16x8*)(Ps + llo * 128 + ((kc * 64 + lhi * 16) ^ swz));

    // O^T += V^T P^T : lane holds q=llo, d = dt*16 + lhi*4 + r
#pragma unroll
    for (int dt = 0; dt < 4; ++dt) {
      const int vrow = dt * 16 + llo;
#pragma unroll
      for (int kc = 0; kc < 2; ++kc) {
        const bf16x8 vf = *(const bf16x8*)(Vs + vrow * 128 + ((kc * 64 + lhi * 16) ^ swz));
        O[dt] = __builtin_amdgcn_mfma_f32_16x16x32_bf16(vf, pb[kc], O[dt], 0, 0, 0);
      }
    }
  }

  const float inv = 1.0f / l;
  const int b = bh >> 4, h = bh & 15;
  u16* crow = ctx + ((size_t)(b * 1024 + q0 + llo)) * 1024 + h * 64;
#pragma unroll
  for (int dt = 0; dt < 4; ++dt) {
    uint2 pk;
    pk.x = pack2(O[dt][0] * inv, O[dt][1] * inv);
    pk.y = pack2(O[dt][2] * inv, O[dt][3] * inv);
    *(uint2*)(crow + dt * 16 + lhi * 4) = pk;
  }
}

// ---------------- LayerNorm over D=1024; writes bf16 and/or fp32 ----------------
__global__ __launch_bounds__(256) void layernorm_k(const float* __restrict__ y,
                                                   const float* __restrict__ g,
                                                   const float* __restrict__ be,
                                                   u16* __restrict__ out_b,
                                                   float* __restrict__ out_f) {
  const int row = blockIdx.x;
  const int t = threadIdx.x;
  const float* yr = y + (size_t)row * 1024;
  const float4 v = *(const float4*)(yr + t * 4);
  float s = v.x + v.y + v.z + v.w;
  float s2 = v.x * v.x + v.y * v.y + v.z * v.z + v.w * v.w;
#pragma unroll
  for (int m = 1; m < 64; m <<= 1) {
    s += __shfl_xor(s, m);
    s2 += __shfl_xor(s2, m);
  }
  __shared__ float red[8];
  const int wv = t >> 6, lane = t & 63;
  if (lane == 0) {
    red[wv * 2] = s;
    red[wv * 2 + 1] = s2;
  }
  __syncthreads();
  s = red[0] + red[2] + red[4] + red[6];
  s2 = red[1] + red[3] + red[5] + red[7];
  const float mu = s * (1.0f / 1024.0f);
  const float var = s2 * (1.0f / 1024.0f) - mu * mu;
  const float inv = rsqrtf(var + 1e-5f);
  const int c = t * 4;
  const float4 gg = *(const float4*)(g + c);
  const float4 bb = *(const float4*)(be + c);
  const float o0 = (v.x - mu) * inv * gg.x + bb.x;
  const float o1 = (v.y - mu) * inv * gg.y + bb.y;
  const float o2 = (v.z - mu) * inv * gg.z + bb.z;
  const float o3 = (v.w - mu) * inv * gg.w + bb.w;
  if (out_f) {
    float4 o = {o0, o1, o2, o3};
    *(float4*)(out_f + (size_t)row * 1024 + c) = o;
  }
  if (out_b) {
    uint2 p;
    p.x = pack2(o0, o1);
    p.y = pack2(o2, o3);
    *(uint2*)(out_b + (size_t)row * 1024 + c) = p;
  }
}

// ---------------- launch ----------------
extern "C" void kernel_launch(void* const* d_in, const int* in_sizes, int n_in,
                              void* d_out, int out_size, void* d_ws, size_t ws_size,
                              hipStream_t stream) {
  const float* X = (const float*)d_in[0];
  const float* W_qkv = (const float*)d_in[1];
  const float* b_qkv = (const float*)d_in[2];
  const float* W_out = (const float*)d_in[3];
  const float* b_out = (const float*)d_in[4];
  const float* ln1_g = (const float*)d_in[5];
  const float* ln1_b = (const float*)d_in[6];
  const float* ln2_g = (const float*)d_in[7];
  const float* ln2_b = (const float*)d_in[8];
  const float* W_ff1 = (const float*)d_in[9];
  const float* b_ff1 = (const float*)d_in[10];
  const float* W_ff2 = (const float*)d_in[11];
  const float* b_ff2 = (const float*)d_in[12];

  char* ws = (char*)d_ws;
  size_t off = 0;
  auto alloc = [&](size_t bytes) {
    char* p = ws + off;
    off += (bytes + 255) & ~(size_t)255;
    return p;
  };
  u16* Xb = (u16*)alloc(8192ull * 1024 * 2);       // X bf16
  u16* Wqkvt = (u16*)alloc(3072ull * 1024 * 2);    // W_qkv^T bf16
  u16* Woutt = (u16*)alloc(1024ull * 1024 * 2);    // W_out^T bf16
  u16* Wff1t = (u16*)alloc(4096ull * 1024 * 2);    // W_ff1^T bf16
  u16* Wff2t = (u16*)alloc(1024ull * 4096 * 2);    // W_ff2^T bf16
  u16* Qb = (u16*)alloc(128ull * 1024 * 64 * 2);   // Q [bh][t][d]
  u16* Kb = (u16*)alloc(128ull * 1024 * 64 * 2);   // K [bh][t][d]
  u16* Vtb = (u16*)alloc(128ull * 1024 * 64 * 2);  // V^T [bh][d][t]
  u16* ctx = (u16*)alloc(8192ull * 1024 * 2);      // attention context bf16
  float* y1 = (float*)alloc(8192ull * 1024 * 4);   // pre-LN1 residual sum; reused as y2
  u16* X1b = (u16*)alloc(8192ull * 1024 * 2);      // LN1 out bf16
  float* X1f = (float*)alloc(8192ull * 1024 * 4);  // LN1 out fp32
  u16* hbuf = Qb;  // FF1 output (64 MB) aliases Qb..ctx (dead after out-proj)

  cast_bf16_k<<<8192, 256, 0, stream>>>(X, Xb);
  transpose_cast_k<<<dim3(96, 32), 256, 0, stream>>>(W_qkv, Wqkvt, 1024, 3072);
  transpose_cast_k<<<dim3(32, 32), 256, 0, stream>>>(W_out, Woutt, 1024, 1024);
  transpose_cast_k<<<dim3(128, 32), 256, 0, stream>>>(W_ff1, Wff1t, 1024, 4096);
  transpose_cast_k<<<dim3(32, 128), 256, 0, stream>>>(W_ff2, Wff2t, 4096, 1024);

  // QKV projection + head scatter
  gemm_bt<0><<<dim3(24, 64), 256, 0, stream>>>(Xb, Wqkvt, b_qkv, nullptr, nullptr, nullptr,
                                               Qb, Kb, Vtb, 8192, 3072, 1024);
  // flash attention
  attn_flash_k<<<dim3(16, 128), 256, 0, stream>>>(Qb, Kb, Vtb, ctx);
  // out projection + bias + residual(X) -> y1 fp32
  gemm_bt<1><<<dim3(8, 64), 256, 0, stream>>>(ctx, Woutt, b_out, X, y1, nullptr,
                                              nullptr, nullptr, nullptr, 8192, 1024, 1024);
  // LN1 -> X1 (bf16 + fp32)
  layernorm_k<<<8192, 256, 0, stream>>>(y1, ln1_g, ln1_b, X1b, X1f);
  // FF1 + bias + exact GELU -> h bf16
  gemm_bt<2><<<dim3(32, 64), 256, 0, stream>>>(X1b, Wff1t, b_ff1, nullptr, nullptr, hbuf,
                                               nullptr, nullptr, nullptr, 8192, 4096, 1024);
  // FF2 + bias + residual(X1) -> y2 fp32 (reuse y1 buffer)
  gemm_bt<1><<<dim3(8, 64), 256, 0, stream>>>(hbuf, Wff2t, b_ff2, X1f, y1, nullptr,
                                              nullptr, nullptr, nullptr, 8192, 1024, 4096);
  // LN2 -> output fp32
  layernorm_k<<<8192, 256, 0, stream>>>(y1, ln2_g, ln2_b, nullptr, (float*)d_out);
}